// Round 1
// 295.838 us; speedup vs baseline: 1.0020x; 1.0020x over previous
//
#include <hip/hip_runtime.h>

// PointPillarScatter (B=4, C=64, 512x512x1 grid, P=120000)
// Invert scatter -> gather:
//   1) memset cell->pillar map (d_ws) to -1              (4 MiB)
//   2) scatter: map[b*cells + cell] = p                  (tiny)
//   3) gather: channel-split (blockIdx.z) so each block does 1024 cells x
//      16 channels. Per thread: 16 fv4 gather loads (one 64B slice per
//      pillar row -> line-local), then 4x4 register transpose and 16
//      nontemporal fv4 stores. Read-burst then write-burst; 4x the wave
//      count of the previous all-64-channel version.

#define G_NX 512
#define G_NY 512
#define G_C 64
#define G_B 4
#define G_CELLS (G_NX * G_NY) // 262144 (nz == 1)

// native clang vector type: __builtin_nontemporal_store requires it
// (HIP's float4 is a struct and is rejected).
typedef float fv4 __attribute__((ext_vector_type(4)));

__global__ __launch_bounds__(256) void ppscatter_map_kernel(
    const int* __restrict__ coords, int* __restrict__ map, int P) {
  int p = blockIdx.x * blockDim.x + threadIdx.x;
  if (p >= P) return;
  int4 cr = ((const int4*)coords)[p]; // [b, z, y, x]
  map[cr.x * G_CELLS + (cr.y + cr.z * G_NX + cr.w)] = p;
}

// grid: (CELLS/1024, B, 4), block 256. Thread owns 4 consecutive cells and
// 16 channels (4 channel-groups starting at cg0 = blockIdx.z * 4).
__global__ __launch_bounds__(256) void ppscatter_gather_kernel(
    const float* __restrict__ feat, const int* __restrict__ map,
    float* __restrict__ out) {
  const int b = blockIdx.y;
  const int cg0 = blockIdx.z * 4; // first channel-group (of 16) this slice
  const int cell0 = blockIdx.x * 1024 + threadIdx.x * 4;

  int4 p4 = *(const int4*)(map + b * G_CELLS + cell0);
  float* orow = out + (size_t)b * (G_C * G_CELLS) +
                (size_t)(4 * cg0) * G_CELLS + cell0;
  const fv4* f4 = (const fv4*)feat; // row p starts at f4[p*16]

  const long q0 = (long)p4.x * 16 + cg0;
  const long q1 = (long)p4.y * 16 + cg0;
  const long q2 = (long)p4.z * 16 + cg0;
  const long q3 = (long)p4.w * 16 + cg0;
  const fv4 z4 = {0.f, 0.f, 0.f, 0.f};

  // Phase 1: read burst. 16 independent 16B loads; per pillar row this
  // thread touches exactly one 64B-aligned slice (cg0*16 .. cg0*16+64).
  fv4 r0[4], r1[4], r2[4], r3[4];
#pragma unroll
  for (int k = 0; k < 4; ++k) {
    r0[k] = (p4.x >= 0) ? f4[q0 + k] : z4;
    r1[k] = (p4.y >= 0) ? f4[q1 + k] : z4;
    r2[k] = (p4.z >= 0) ? f4[q2 + k] : z4;
    r3[k] = (p4.w >= 0) ? f4[q3 + k] : z4;
  }

  // Phase 2: write burst. 4x4 register transpose per channel-group, then
  // 4 NT stores (4 cells wide each).
#pragma unroll
  for (int k = 0; k < 4; ++k) {
    fv4 s0 = {r0[k].x, r1[k].x, r2[k].x, r3[k].x};
    fv4 s1 = {r0[k].y, r1[k].y, r2[k].y, r3[k].y};
    fv4 s2 = {r0[k].z, r1[k].z, r2[k].z, r3[k].z};
    fv4 s3 = {r0[k].w, r1[k].w, r2[k].w, r3[k].w};
    float* oc = orow + (size_t)(4 * k) * G_CELLS;
    __builtin_nontemporal_store(s0, (fv4*)(oc + 0 * (size_t)G_CELLS));
    __builtin_nontemporal_store(s1, (fv4*)(oc + 1 * (size_t)G_CELLS));
    __builtin_nontemporal_store(s2, (fv4*)(oc + 2 * (size_t)G_CELLS));
    __builtin_nontemporal_store(s3, (fv4*)(oc + 3 * (size_t)G_CELLS));
  }
}

extern "C" void kernel_launch(void* const* d_in, const int* in_sizes, int n_in,
                              void* d_out, int out_size, void* d_ws, size_t ws_size,
                              hipStream_t stream) {
  const float* feat = (const float*)d_in[0];   // [P, 64] fp32
  const int* coords = (const int*)d_in[1];     // [P, 4] int32
  float* out = (float*)d_out;                  // [4, 64, 512, 512] fp32

  const int P = in_sizes[0] / G_C;
  int* map = (int*)d_ws; // B*CELLS int32 = 4 MiB

  (void)hipMemsetAsync(map, 0xFF, (size_t)G_B * G_CELLS * sizeof(int), stream);
  ppscatter_map_kernel<<<(P + 255) / 256, 256, 0, stream>>>(coords, map, P);
  ppscatter_gather_kernel<<<dim3(G_CELLS / 1024, G_B, 4), 256, 0, stream>>>(
      feat, map, out);
}